// Round 4
// baseline (199.225 us; speedup 1.0000x reference)
//
#include <hip/hip_runtime.h>
#include <hip/hip_bf16.h>

#define BATCH 2
#define SEQL 2048
#define NH 16
#define DH 64
#define DM 1024
// Q pre-scale folded into qkv_gemm epilogue: 1/sqrt(64) * log2(e)
#define QSCALE 0.1803368801111244f

typedef __hip_bfloat16 bf16;
typedef __attribute__((ext_vector_type(8)))  short bf16x8;
typedef __attribute__((ext_vector_type(4)))  float f32x4;
typedef __attribute__((ext_vector_type(16))) float f32x16;

__device__ __forceinline__ void gl_lds16(const void* g, void* l) {
    __builtin_amdgcn_global_load_lds(
        (const __attribute__((address_space(1))) unsigned int*)g,
        (__attribute__((address_space(3))) unsigned int*)l, 16, 0, 0);
}

__device__ __forceinline__ unsigned int pkbf(float a, float b) {
    union { bf16 h[2]; unsigned int u; } x;
    x.h[0] = __float2bfloat16(a); x.h[1] = __float2bfloat16(b);
    return x.u;
}

// ---------------------------------------------------------------------------
// Prep (fused): z<4 -> weight transpose to bf16 Bt[n][k]; z==4 -> x fp32->bf16
// (grid-stride). grid (16,16,5), block 256.
// ---------------------------------------------------------------------------
__global__ __launch_bounds__(256) void prep_kernel(
    const float* __restrict__ x,
    const float* __restrict__ Wq, const float* __restrict__ Wk,
    const float* __restrict__ Wv, const float* __restrict__ Wo,
    bf16* __restrict__ Wt, bf16* __restrict__ xb)
{
    const int zi = blockIdx.z;
    if (zi == 4) {
        const int bid = blockIdx.y * 16 + blockIdx.x;
        const size_t base = ((size_t)bid * 256 + threadIdx.x) * 4;
        #pragma unroll
        for (int it = 0; it < 16; ++it) {
            const size_t i = base + (size_t)it * 262144;
            const float4 v = *(const float4*)(x + i);
            bf16 o[4];
            o[0] = __float2bfloat16(v.x); o[1] = __float2bfloat16(v.y);
            o[2] = __float2bfloat16(v.z); o[3] = __float2bfloat16(v.w);
            *(uint2*)(xb + i) = *(const uint2*)o;
        }
        return;
    }

    __shared__ float ts[64][65];
    const float* src = (zi == 0) ? Wq : (zi == 1) ? Wk : (zi == 2) ? Wv : Wo;
    bf16* dst = Wt + (size_t)zi * DM * DM;
    const int row0 = blockIdx.y * 64;
    const int col0 = blockIdx.x * 64;
    const int tx = threadIdx.x & 63;
    const int ty = threadIdx.x >> 6;

    if (zi < 3) {
        const int h = col0 >> 6;
        #pragma unroll
        for (int i = 0; i < 16; ++i) {
            const int r = ty + 4 * i;
            ts[r][tx] = src[h * (DM * DH) + (row0 + r) * DH + tx];
        }
    } else {
        #pragma unroll
        for (int i = 0; i < 16; ++i) {
            const int r = ty + 4 * i;
            ts[r][tx] = src[(size_t)(row0 + r) * DM + col0 + tx];
        }
    }
    __syncthreads();
    #pragma unroll
    for (int i = 0; i < 16; ++i) {
        const int rr = ty + 4 * i;
        dst[(size_t)(col0 + rr) * DM + row0 + tx] = __float2bfloat16(ts[tx][rr]);
    }
}

// ---------------------------------------------------------------------------
// QKV GEMM v3 (round-10 config): 2 K-steps per barrier, round-6 epilogue.
// grid (8, 32, 3), block 256.
// ---------------------------------------------------------------------------
__global__ __launch_bounds__(256) void qkv_gemm(
    const bf16* __restrict__ xb, const bf16* __restrict__ Wt,
    const float* __restrict__ bq, const float* __restrict__ bk, const float* __restrict__ bv,
    bf16* __restrict__ qkv)
{
    __shared__ __align__(16) bf16 As[2][128 * 32];
    __shared__ __align__(16) bf16 Bs[2][128 * 32];

    const int t = threadIdx.x;
    const int lane = t & 63, w = t >> 6;
    const int ml = lane & 15, quad = lane >> 4;
    const int wr = w >> 1, wc = w & 1;
    const int bn = blockIdx.x, bm = blockIdx.y, which = blockIdx.z;

    const bf16* A0 = xb + (size_t)(bm * 128) * DM;
    const bf16* B0 = Wt + (size_t)which * DM * DM + (size_t)(bn * 128) * DM;
    const float* bias = (which == 0) ? bq : (which == 1) ? bk : bv;
    bf16* outb = qkv + (size_t)which * (BATCH * SEQL * NH * DH);
    const float oscale = (which == 0) ? QSCALE : 1.0f;

    f32x4 acc[4][4];
    #pragma unroll
    for (int i = 0; i < 4; ++i)
        #pragma unroll
        for (int j = 0; j < 4; ++j) acc[i][j] = (f32x4){0.f, 0.f, 0.f, 0.f};

    const int r0 = t >> 2, c0 = (t & 3) * 8;
    const int f1 = t + 256;
    const int r1 = f1 >> 2, c1 = (f1 & 3) * 8;

    for (int kt = 0; kt < DM / 64; ++kt) {
        const int k0 = kt * 64;
        __syncthreads();
        #pragma unroll
        for (int half = 0; half < 2; ++half) {
            const int kh = k0 + half * 32;
            gl_lds16(A0 + (size_t)r0 * DM + kh + c0, &As[half][t * 8]);
            gl_lds16(A0 + (size_t)r1 * DM + kh + c1, &As[half][f1 * 8]);
            gl_lds16(B0 + (size_t)r0 * DM + kh + c0, &Bs[half][t * 8]);
            gl_lds16(B0 + (size_t)r1 * DM + kh + c1, &Bs[half][f1 * 8]);
        }
        __syncthreads();
        #pragma unroll
        for (int half = 0; half < 2; ++half) {
            bf16x8 af[4], bfr[4];
            #pragma unroll
            for (int i = 0; i < 4; ++i)
                af[i] = *(const bf16x8*)&As[half][(wr * 64 + i * 16 + ml) * 32 + quad * 8];
            #pragma unroll
            for (int j = 0; j < 4; ++j)
                bfr[j] = *(const bf16x8*)&Bs[half][(wc * 64 + j * 16 + ml) * 32 + quad * 8];
            #pragma unroll
            for (int i = 0; i < 4; ++i)
                #pragma unroll
                for (int j = 0; j < 4; ++j)
                    acc[i][j] = __builtin_amdgcn_mfma_f32_16x16x32_bf16(af[i], bfr[j], acc[i][j], 0, 0, 0);
        }
    }

    float bb[4];
    #pragma unroll
    for (int j = 0; j < 4; ++j) bb[j] = bias[bn * 128 + wc * 64 + j * 16 + ml];

    if (which == 2) {
        #pragma unroll
        for (int i = 0; i < 4; ++i) {
            const int row0v = bm * 128 + wr * 64 + i * 16 + quad * 4;
            const int b = row0v >> 11;
            const int s0 = row0v & (SEQL - 1);
            #pragma unroll
            for (int j = 0; j < 4; ++j) {
                const int col = bn * 128 + wc * 64 + j * 16 + ml;
                const int h = col >> 6, d = col & 63;
                bf16 tmp[4];
                #pragma unroll
                for (int rg = 0; rg < 4; ++rg)
                    tmp[rg] = __float2bfloat16(acc[i][j][rg] + bb[j]);
                *(uint2*)&outb[(((size_t)(b * NH + h)) * DH + d) * SEQL + s0] =
                    *(const uint2*)tmp;
            }
        }
    } else {
        #pragma unroll
        for (int i = 0; i < 4; ++i) {
            #pragma unroll
            for (int rg = 0; rg < 4; ++rg) {
                const int row = bm * 128 + wr * 64 + i * 16 + quad * 4 + rg;
                const int b = row >> 11;
                const int s = row & (SEQL - 1);
                #pragma unroll
                for (int j = 0; j < 4; ++j) {
                    const int col = bn * 128 + wc * 64 + j * 16 + ml;
                    const int h = col >> 6, d = col & 63;
                    outb[(((size_t)(b * NH + h)) * SEQL + s) * DH + d] =
                        __float2bfloat16((acc[i][j][rg] + bb[j]) * oscale);
                }
            }
        }
    }
}

// ---------------------------------------------------------------------------
// O-proj GEMM v3: 128x64 tiles, 2 K-steps per barrier. grid (16,32), block 256.
// ---------------------------------------------------------------------------
__global__ __launch_bounds__(256) void oproj_gemm(
    const bf16* __restrict__ zb, const bf16* __restrict__ Bt,
    const float* __restrict__ bo, float* __restrict__ out)
{
    __shared__ __align__(16) bf16 As[2][128 * 32];
    __shared__ __align__(16) bf16 Bs[2][64 * 32];

    const int t = threadIdx.x;
    const int lane = t & 63, w = t >> 6;
    const int ml = lane & 15, quad = lane >> 4;
    const int wr = w >> 1, wc = w & 1;
    const int bn = blockIdx.x, bm = blockIdx.y;

    const bf16* A0 = zb + (size_t)(bm * 128) * DM;
    const bf16* B0 = Bt + (size_t)(bn * 64) * DM;

    f32x4 acc[4][2];
    #pragma unroll
    for (int i = 0; i < 4; ++i)
        #pragma unroll
        for (int j = 0; j < 2; ++j) acc[i][j] = (f32x4){0.f, 0.f, 0.f, 0.f};

    const int r0 = t >> 2, c0 = (t & 3) * 8;
    const int f1 = t + 256;
    const int r1 = f1 >> 2, c1 = (f1 & 3) * 8;

    for (int kt = 0; kt < DM / 64; ++kt) {
        const int k0 = kt * 64;
        __syncthreads();
        #pragma unroll
        for (int half = 0; half < 2; ++half) {
            const int kh = k0 + half * 32;
            gl_lds16(A0 + (size_t)r0 * DM + kh + c0, &As[half][t * 8]);
            gl_lds16(A0 + (size_t)r1 * DM + kh + c1, &As[half][f1 * 8]);
            gl_lds16(B0 + (size_t)r0 * DM + kh + c0, &Bs[half][t * 8]);
        }
        __syncthreads();
        #pragma unroll
        for (int half = 0; half < 2; ++half) {
            bf16x8 af[4], bfr[2];
            #pragma unroll
            for (int i = 0; i < 4; ++i)
                af[i] = *(const bf16x8*)&As[half][(wr * 64 + i * 16 + ml) * 32 + quad * 8];
            #pragma unroll
            for (int j = 0; j < 2; ++j)
                bfr[j] = *(const bf16x8*)&Bs[half][(wc * 32 + j * 16 + ml) * 32 + quad * 8];
            #pragma unroll
            for (int i = 0; i < 4; ++i)
                #pragma unroll
                for (int j = 0; j < 2; ++j)
                    acc[i][j] = __builtin_amdgcn_mfma_f32_16x16x32_bf16(af[i], bfr[j], acc[i][j], 0, 0, 0);
        }
    }

    float bb[2];
    #pragma unroll
    for (int j = 0; j < 2; ++j) bb[j] = bo[bn * 64 + wc * 32 + j * 16 + ml];

    #pragma unroll
    for (int i = 0; i < 4; ++i) {
        #pragma unroll
        for (int rg = 0; rg < 4; ++rg) {
            const int row = bm * 128 + wr * 64 + i * 16 + quad * 4 + rg;
            #pragma unroll
            for (int j = 0; j < 2; ++j) {
                const int col = bn * 64 + wc * 32 + j * 16 + ml;
                out[(size_t)row * DM + col] = acc[i][j][rg] + bb[j];
            }
        }
    }
}

// ---------------------------------------------------------------------------
// MFMA flash attention v10: SMALL Q-TILES for grid-limited-occupancy fix.
// q-tile = 32 rows/block -> grid (bh=32, qt=64) = 2048 blocks (was 1024),
// KV staged in 128-row chunks; the 4 waves each own a 32-kv subrange of the
// chunk (kvg = w). Swapped QK^T + in-register P (v9 machinery) per wave.
// l folded into an extra ones-A MFMA (all lanes hold the full row-sum; no
// VALU adds, no epilogue shuffle). Partial z/l across the 4 waves combined
// once at the end via LDS (no-max softmax => plain addition; no global ws).
// Single-buffered LDS 32KB (prefetch proven neutral r1/r2) -> 5 blocks/CU;
// 2048 blocks -> ~2x occupancy vs v9, tail halves (<=16 iters/block).
// V^T tile is [64][128] w/ 16-deep XOR swizzle -> PV reads 2-way (free).
// grid = (32, 64) with qt reversed (big blocks first), block 256.
// ---------------------------------------------------------------------------
__global__ __launch_bounds__(256) void attn_kernel(
    const bf16* __restrict__ qg, const bf16* __restrict__ kg, const bf16* __restrict__ vtg,
    bf16* __restrict__ z)
{
    __shared__ __align__(16) bf16 SM[128 * 64 + 64 * 128];   // K 16KB | V^T 16KB
    bf16* Ks = SM;             // [128 kv][64 d], 16B chunks XOR'd with (row&7)
    bf16* Vt = SM + 128 * 64;  // [64 d][128 kv], 16B chunks XOR'd with (row&15)

    const int t    = threadIdx.x;
    const int lane = t & 63;
    const int w    = t >> 6;          // kv-group 0..3
    const int q5   = lane & 31;       // q column (and A-operand row)
    const int hl   = lane >> 5;       // lane half (k-slice)

    const int bh = blockIdx.x;
    const int b  = bh >> 4;
    const int h  = bh & 15;
    const int qt = 63 - (int)blockIdx.y;   // 0..63, longest blocks launch first
    const int q0 = qt * 32;
    const int iters = (qt >> 2) + 1;       // ceil((qt+1)*32 / 128)

    const size_t base   = (size_t)bh * SEQL * DH;  // q/k base ([b,h,s,d])
    const size_t vtbase = (size_t)bh * DH * SEQL;  // v^T base ([b,h,d,s])

    // staging slots: 256 thr x 4 slots x 16B per array (1024 slots = 16KB)
    int krow[4], kcol[4], vrow[4], vcol[4];
    #pragma unroll
    for (int i = 0; i < 4; ++i) {
        const int s = t + 256 * i;
        krow[i] = s >> 3;  kcol[i] = (s & 7)  ^ (krow[i] & 7);
        vrow[i] = s >> 4;  vcol[i] = (s & 15) ^ (vrow[i] & 15);
    }

    // Q as persistent B-operand frags: Q[q0+q5][s*16 + hl*8 + j], s=0..3
    bf16x8 aq[4];
    {
        const bf16* qp = qg + base + (size_t)(q0 + q5) * DH;
        #pragma unroll
        for (int s = 0; s < 4; ++s)
            aq[s] = *(const bf16x8*)(qp + s * 16 + hl * 8);
    }

    const short o1 = (short)0x3F80;
    const bf16x8 onesA = {o1, o1, o1, o1, o1, o1, o1, o1};

    f32x16 zacc[2];
    #pragma unroll
    for (int dg = 0; dg < 2; ++dg)
        #pragma unroll
        for (int r = 0; r < 16; ++r) zacc[dg][r] = 0.f;
    f32x16 laccv;
    #pragma unroll
    for (int r = 0; r < 16; ++r) laccv[r] = 0.f;

    for (int it = 0; it < iters; ++it) {
        const int kc = it * 128;
        if (it) __syncthreads();          // previous chunk's reads complete
        #pragma unroll
        for (int i = 0; i < 4; ++i) {
            gl_lds16(kg + base + (size_t)(kc + krow[i]) * DH + kcol[i] * 8,
                     &Ks[(t + 256 * i) * 8]);
            gl_lds16(vtg + vtbase + (size_t)vrow[i] * SEQL + kc + vcol[i] * 8,
                     &Vt[(t + 256 * i) * 8]);
        }
        __syncthreads();                  // staging visible (vmcnt drain)

        const int kvbase = kc + w * 32;   // this wave's kv subrange start
        if (kvbase <= q0 + 31) {          // not fully masked
            // ---- S^T = K · Q^T : 32kv x 32q per wave, 4 k-steps over d ----
            f32x16 sc;
            #pragma unroll
            for (int r = 0; r < 16; ++r) sc[r] = 0.f;
            {
                const int krw = w * 32 + q5;
                const int krx = krw & 7;
                __builtin_amdgcn_s_setprio(1);
                #pragma unroll
                for (int s = 0; s < 4; ++s) {
                    const int cc = (s * 2 + hl) ^ krx;
                    const bf16x8 ak = *(const bf16x8*)(&Ks[krw * 64 + cc * 8]);
                    sc = __builtin_amdgcn_mfma_f32_32x32x16_bf16(ak, aq[s], sc, 0, 0, 0);
                }
                __builtin_amdgcn_s_setprio(0);
            }

            // ---- causal mask (only the diagonal-straddling wave-chunk) ----
            if (it == iters - 1 && kvbase + 31 > q0) {
                #pragma unroll
                for (int r = 0; r < 16; ++r) {
                    const int kvloc = (r & 3) + 8 * (r >> 2) + 4 * hl;
                    sc[r] = (kvbase + kvloc > q0 + q5) ? -1e30f : sc[r];
                }
            }

            // ---- p = 2^s (lane-local), pack to bf16 words ----
            unsigned int wpk[8];
            #pragma unroll
            for (int g = 0; g < 4; ++g) {
                const float p0 = __builtin_exp2f(sc[4 * g + 0]);
                const float p1 = __builtin_exp2f(sc[4 * g + 1]);
                const float p2 = __builtin_exp2f(sc[4 * g + 2]);
                const float p3 = __builtin_exp2f(sc[4 * g + 3]);
                wpk[2 * g + 0] = pkbf(p0, p1);
                wpk[2 * g + 1] = pkbf(p2, p3);
            }

            // ---- assemble PV B-frags: lane<->lane^32 half-swap ----
            bf16x8 pf[2];
            #pragma unroll
            for (int ks = 0; ks < 2; ++ks) {
                const unsigned int S0 = hl ? wpk[4 * ks + 0] : wpk[4 * ks + 2];
                const unsigned int S1 = hl ? wpk[4 * ks + 1] : wpk[4 * ks + 3];
                const unsigned int R0 = __shfl_xor((int)S0, 32);
                const unsigned int R1 = __shfl_xor((int)S1, 32);
                union { unsigned int u[4]; bf16x8 v; } f;
                f.u[0] = hl ? R0 : wpk[4 * ks + 0];
                f.u[1] = hl ? R1 : wpk[4 * ks + 1];
                f.u[2] = hl ? wpk[4 * ks + 2] : R0;
                f.u[3] = hl ? wpk[4 * ks + 3] : R1;
                pf[ks] = f.v;
            }

            // ---- l += ones·P (MFMA), Z^T += V^T · P^T ----
            __builtin_amdgcn_s_setprio(1);
            #pragma unroll
            for (int ks = 0; ks < 2; ++ks) {
                laccv = __builtin_amdgcn_mfma_f32_32x32x16_bf16(onesA, pf[ks], laccv, 0, 0, 0);
                #pragma unroll
                for (int dg = 0; dg < 2; ++dg) {
                    const int row = dg * 32 + q5;        // V^T row (d)
                    const int cc  = (w * 4 + ks * 2 + hl) ^ (row & 15);
                    const bf16x8 av = *(const bf16x8*)(&Vt[row * 128 + cc * 8]);
                    zacc[dg] = __builtin_amdgcn_mfma_f32_32x32x16_bf16(av, pf[ks], zacc[dg], 0, 0, 0);
                }
            }
            __builtin_amdgcn_s_setprio(0);
        }
    }

    // ---- epilogue: combine the 4 waves' kv partials via LDS ----
    __syncthreads();   // compute done; K/V LDS reusable as f32 scratch (8192 f32)
    float* sp = (float*)SM;
    if (w > 0) {
        float* zp = sp + (size_t)(w - 1) * 2048;
        #pragma unroll
        for (int dg = 0; dg < 2; ++dg)
            #pragma unroll
            for (int r = 0; r < 16; ++r)
                zp[(dg * 16 + r) * 64 + lane] = zacc[dg][r];
        sp[6144 + (w - 1) * 64 + lane] = laccv[0];
    }
    __syncthreads();
    if (w == 0) {
        #pragma unroll
        for (int p = 0; p < 3; ++p)
            #pragma unroll
            for (int dg = 0; dg < 2; ++dg)
                #pragma unroll
                for (int r = 0; r < 16; ++r)
                    zacc[dg][r] += sp[p * 2048 + (dg * 16 + r) * 64 + lane];
        const float l = laccv[0] + sp[6144 + lane] + sp[6144 + 64 + lane]
                                 + sp[6144 + 128 + lane];
        const float invl = 1.f / l;

        bf16* zp = z + (((size_t)b * SEQL + q0 + q5) * NH + h) * DH;
        #pragma unroll
        for (int dg = 0; dg < 2; ++dg) {
            #pragma unroll
            for (int g2 = 0; g2 < 4; ++g2) {
                bf16 tmp[4];
                #pragma unroll
                for (int j = 0; j < 4; ++j)
                    tmp[j] = __float2bfloat16(zacc[dg][4 * g2 + j] * invl);
                *(uint2*)(zp + dg * 32 + 8 * g2 + 4 * hl) = *(const uint2*)tmp;
            }
        }
    }
}

// ---------------------------------------------------------------------------
extern "C" void kernel_launch(void* const* d_in, const int* in_sizes, int n_in,
                              void* d_out, int out_size, void* d_ws, size_t ws_size,
                              hipStream_t stream)
{
    const float* x  = (const float*)d_in[0];
    const float* Wq = (const float*)d_in[1];
    const float* Wk = (const float*)d_in[2];
    const float* Wv = (const float*)d_in[3];
    const float* Wo = (const float*)d_in[4];
    const float* bq = (const float*)d_in[5];
    const float* bk = (const float*)d_in[6];
    const float* bv = (const float*)d_in[7];
    const float* bo = (const float*)d_in[8];
    float* out = (float*)d_out;

    const size_t TOK = (size_t)BATCH * SEQL;             // 4096
    const size_t QKV = TOK * DM;                         // 4M elems
    bf16* xb  = (bf16*)d_ws;                             // 4M
    bf16* Wt  = xb + QKV;                                // 4 x 1M
    bf16* qkv = Wt + 4 * (size_t)DM * DM;                // 3 x 4M
    bf16* zb  = qkv + 3 * QKV;                           // 4M   (48 MB total)

    prep_kernel<<<dim3(16, 16, 5), 256, 0, stream>>>(x, Wq, Wk, Wv, Wo, Wt, xb);
    qkv_gemm<<<dim3(8, 32, 3), 256, 0, stream>>>(xb, Wt, bq, bk, bv, qkv);
    attn_kernel<<<dim3(BATCH * NH, SEQL / 32), 256, 0, stream>>>(
        qkv, qkv + QKV, qkv + 2 * QKV, zb);
    oproj_gemm<<<dim3(16, 32), 256, 0, stream>>>(zb, Wt + 3 * (size_t)DM * DM, bo, out);
}

// Round 5
// 187.692 us; speedup vs baseline: 1.0614x; 1.0614x over previous
//
#include <hip/hip_runtime.h>
#include <hip/hip_bf16.h>

#define BATCH 2
#define SEQL 2048
#define NH 16
#define DH 64
#define DM 1024
#define LDK 72   // attn P-tile LDS row stride (bf16)
// Q pre-scale folded into qkv_gemm epilogue: 1/sqrt(64) * log2(e)
#define QSCALE 0.1803368801111244f

typedef __hip_bfloat16 bf16;
typedef __attribute__((ext_vector_type(8)))  short bf16x8;
typedef __attribute__((ext_vector_type(4)))  float f32x4;

__device__ __forceinline__ void gl_lds16(const void* g, void* l) {
    __builtin_amdgcn_global_load_lds(
        (const __attribute__((address_space(1))) unsigned int*)g,
        (__attribute__((address_space(3))) unsigned int*)l, 16, 0, 0);
}

// ---------------------------------------------------------------------------
// Prep (fused): z<4 -> weight transpose to bf16 Bt[n][k]; z==4 -> x fp32->bf16
// (grid-stride). grid (16,16,5), block 256.
// ---------------------------------------------------------------------------
__global__ __launch_bounds__(256) void prep_kernel(
    const float* __restrict__ x,
    const float* __restrict__ Wq, const float* __restrict__ Wk,
    const float* __restrict__ Wv, const float* __restrict__ Wo,
    bf16* __restrict__ Wt, bf16* __restrict__ xb)
{
    const int zi = blockIdx.z;
    if (zi == 4) {
        const int bid = blockIdx.y * 16 + blockIdx.x;
        const size_t base = ((size_t)bid * 256 + threadIdx.x) * 4;
        #pragma unroll
        for (int it = 0; it < 16; ++it) {
            const size_t i = base + (size_t)it * 262144;
            const float4 v = *(const float4*)(x + i);
            bf16 o[4];
            o[0] = __float2bfloat16(v.x); o[1] = __float2bfloat16(v.y);
            o[2] = __float2bfloat16(v.z); o[3] = __float2bfloat16(v.w);
            *(uint2*)(xb + i) = *(const uint2*)o;
        }
        return;
    }

    __shared__ float ts[64][65];
    const float* src = (zi == 0) ? Wq : (zi == 1) ? Wk : (zi == 2) ? Wv : Wo;
    bf16* dst = Wt + (size_t)zi * DM * DM;
    const int row0 = blockIdx.y * 64;
    const int col0 = blockIdx.x * 64;
    const int tx = threadIdx.x & 63;
    const int ty = threadIdx.x >> 6;

    if (zi < 3) {
        const int h = col0 >> 6;
        #pragma unroll
        for (int i = 0; i < 16; ++i) {
            const int r = ty + 4 * i;
            ts[r][tx] = src[h * (DM * DH) + (row0 + r) * DH + tx];
        }
    } else {
        #pragma unroll
        for (int i = 0; i < 16; ++i) {
            const int r = ty + 4 * i;
            ts[r][tx] = src[(size_t)(row0 + r) * DM + col0 + tx];
        }
    }
    __syncthreads();
    #pragma unroll
    for (int i = 0; i < 16; ++i) {
        const int rr = ty + 4 * i;
        dst[(size_t)(col0 + rr) * DM + row0 + tx] = __float2bfloat16(ts[tx][rr]);
    }
}

// ---------------------------------------------------------------------------
// QKV GEMM v4: fused over N=3072 (q|k|v), BM=BN=256, BK=64, 8 waves (2Mx4N),
// 128KB LDS double-buffer, 4-phase-per-K-tile schedule with COUNTED vmcnt
// (never 0 mid-loop), raw s_barrier (no compiler vmcnt-drain), progressive
// half-tile staging into just-freed LDS halves, 8-deep XOR swizzle (2-way
// ds_read_b128 = free), s_setprio around each 16-MFMA cluster, XCD-swizzled
// 192-block grid. grid (12,16), block 512.
// ---------------------------------------------------------------------------
__global__ __launch_bounds__(512, 2) void qkv_gemm(
    const bf16* __restrict__ xb, const bf16* __restrict__ Wt,
    const float* __restrict__ bq, const float* __restrict__ bk, const float* __restrict__ bv,
    bf16* __restrict__ qkv)
{
    // [buf][row 0..255][chunk-swizzled 64 bf16]; halves of 128 rows = 8192 bf16
    __shared__ __align__(16) bf16 As[2][256 * 64];   // 2 x 32 KB
    __shared__ __align__(16) bf16 Bs[2][256 * 64];   // 2 x 32 KB

    const int t = threadIdx.x;            // 0..511
    const int lane = t & 63, w = t >> 6;  // 8 waves
    const int ml = lane & 15, quad = lane >> 4;
    const int mlx = ml & 7;
    const int wr = w >> 2, wc = w & 3;    // 2 (M) x 4 (N)

    // XCD-aware block swizzle (192 = 8 XCDs x 24)
    const int bid0 = blockIdx.y * 12 + blockIdx.x;
    const int bid  = (bid0 & 7) * 24 + (bid0 >> 3);
    const int bn = bid % 12, bm = bid / 12;

    const bf16* A0 = xb + (size_t)bm * 256 * DM;
    const bf16* B0 = Wt + (size_t)bn * 256 * DM;

    // staging geometry: slot s in [0,2048) per array; thread covers s = t,t+512
    // per half (1024 slots). row_local = s>>3, chunk stored at s&7 holds global
    // chunk (s&7)^(row&7)  [pre-swizzled source, linear dest - rule 21]
    const int sr = t >> 3;                 // 0..63
    const int sc = (t & 7) ^ (sr & 7);

#define STG(Xs_buf, X0, h, kk) do {                                           \
    gl_lds16((X0) + (size_t)((h) * 128 + sr) * DM + (kk) + sc * 8,            \
             (Xs_buf) + (h) * 8192 + t * 8);                                  \
    gl_lds16((X0) + (size_t)((h) * 128 + 64 + sr) * DM + (kk) + sc * 8,       \
             (Xs_buf) + (h) * 8192 + 4096 + t * 8);                           \
} while (0)

    f32x4 acc[8][4];
    #pragma unroll
    for (int i = 0; i < 8; ++i)
        #pragma unroll
        for (int j = 0; j < 4; ++j) acc[i][j] = (f32x4){0.f, 0.f, 0.f, 0.f};

    // prologue: stage tiles 0 and 1, wait for tile 0 (8 of 16 outstanding)
    STG(As[0], A0, 0, 0); STG(As[0], A0, 1, 0);
    STG(Bs[0], B0, 0, 0); STG(Bs[0], B0, 1, 0);
    STG(As[1], A0, 0, 64); STG(As[1], A0, 1, 64);
    STG(Bs[1], B0, 0, 64); STG(Bs[1], B0, 1, 64);
    asm volatile("s_waitcnt vmcnt(8)" ::: "memory");
    __builtin_amdgcn_s_barrier();

    const int T = DM / 64;   // 16 K-tiles
    for (int kt = 0; kt < T; ++kt) {
        const int cur = kt & 1;
        const bf16* Ac = As[cur];
        const bf16* Bc = Bs[cur];
        bf16* Asn = As[cur];   // t+2 shares parity -> stage into cur buffers
        bf16* Bsn = Bs[cur];
        const bool st = (kt + 2 < T);
        const int kk2 = (kt + 2) * 64;

        bf16x8 af[4][2];          // A frags of current mh (reused)
        bf16x8 bfr[2][2][2];      // [nh][j][ks], held across phases

        // ---- ph0: (mh0, nh0) ----
        #pragma unroll
        for (int i = 0; i < 4; ++i)
            #pragma unroll
            for (int ks = 0; ks < 2; ++ks)
                af[i][ks] = *(const bf16x8*)&Ac[(wr * 64 + i * 16 + ml) * 64 +
                                                (((ks << 2) + quad) ^ mlx) * 8];
        #pragma unroll
        for (int j = 0; j < 2; ++j)
            #pragma unroll
            for (int ks = 0; ks < 2; ++ks)
                bfr[0][j][ks] = *(const bf16x8*)&Bc[(wc * 32 + j * 16 + ml) * 64 +
                                                    (((ks << 2) + quad) ^ mlx) * 8];
        __builtin_amdgcn_s_setprio(1);
        #pragma unroll
        for (int i = 0; i < 4; ++i)
            #pragma unroll
            for (int j = 0; j < 2; ++j)
                #pragma unroll
                for (int ks = 0; ks < 2; ++ks)
                    acc[i][j] = __builtin_amdgcn_mfma_f32_16x16x32_bf16(
                        af[i][ks], bfr[0][j][ks], acc[i][j], 0, 0, 0);
        __builtin_amdgcn_s_setprio(0);
        __builtin_amdgcn_s_barrier();

        // ---- ph1: (mh0, nh1); stage A-h0 + B-h0 of tile kt+2 ----
        #pragma unroll
        for (int j = 0; j < 2; ++j)
            #pragma unroll
            for (int ks = 0; ks < 2; ++ks)
                bfr[1][j][ks] = *(const bf16x8*)&Bc[(128 + wc * 32 + j * 16 + ml) * 64 +
                                                    (((ks << 2) + quad) ^ mlx) * 8];
        if (st) { STG(Asn, A0, 0, kk2); STG(Bsn, B0, 0, kk2); }
        __builtin_amdgcn_s_setprio(1);
        #pragma unroll
        for (int i = 0; i < 4; ++i)
            #pragma unroll
            for (int j = 0; j < 2; ++j)
                #pragma unroll
                for (int ks = 0; ks < 2; ++ks)
                    acc[i][2 + j] = __builtin_amdgcn_mfma_f32_16x16x32_bf16(
                        af[i][ks], bfr[1][j][ks], acc[i][2 + j], 0, 0, 0);
        __builtin_amdgcn_s_setprio(0);
        __builtin_amdgcn_s_barrier();

        // ---- ph2: (mh1, nh1); stage B-h1 ----
        #pragma unroll
        for (int i = 0; i < 4; ++i)
            #pragma unroll
            for (int ks = 0; ks < 2; ++ks)
                af[i][ks] = *(const bf16x8*)&Ac[(128 + wr * 64 + i * 16 + ml) * 64 +
                                                (((ks << 2) + quad) ^ mlx) * 8];
        if (st) { STG(Bsn, B0, 1, kk2); }
        __builtin_amdgcn_s_setprio(1);
        #pragma unroll
        for (int i = 0; i < 4; ++i)
            #pragma unroll
            for (int j = 0; j < 2; ++j)
                #pragma unroll
                for (int ks = 0; ks < 2; ++ks)
                    acc[4 + i][2 + j] = __builtin_amdgcn_mfma_f32_16x16x32_bf16(
                        af[i][ks], bfr[1][j][ks], acc[4 + i][2 + j], 0, 0, 0);
        __builtin_amdgcn_s_setprio(0);
        __builtin_amdgcn_s_barrier();

        // ---- ph3: (mh1, nh0) with held bfr[0]; stage A-h1; counted vmcnt ----
        if (st) { STG(Asn, A0, 1, kk2); }
        __builtin_amdgcn_s_setprio(1);
        #pragma unroll
        for (int i = 0; i < 4; ++i)
            #pragma unroll
            for (int j = 0; j < 2; ++j)
                #pragma unroll
                for (int ks = 0; ks < 2; ++ks)
                    acc[4 + i][j] = __builtin_amdgcn_mfma_f32_16x16x32_bf16(
                        af[i][ks], bfr[0][j][ks], acc[4 + i][j], 0, 0, 0);
        __builtin_amdgcn_s_setprio(0);

        if (kt < T - 2) {
            asm volatile("s_waitcnt vmcnt(8)" ::: "memory");   // tile kt+1 landed
        } else if (kt == T - 2) {
            asm volatile("s_waitcnt vmcnt(0)" ::: "memory");   // final tile landed
        }
        if (kt < T - 1) __builtin_amdgcn_s_barrier();
    }
#undef STG

    // ---- epilogue ----
    const int which = bn >> 2;                       // 0:q 1:k 2:v
    const float* bias = (which == 0) ? bq : (which == 1) ? bk : bv;
    bf16* outb = qkv + (size_t)which * (BATCH * SEQL * NH * DH);
    const float oscale = (which == 0) ? QSCALE : 1.0f;
    const int colbase = (bn & 3) * 256;

    if (which == 2) {
        #pragma unroll
        for (int mh = 0; mh < 2; ++mh)
            #pragma unroll
            for (int i = 0; i < 4; ++i) {
                const int row0v = bm * 256 + mh * 128 + wr * 64 + i * 16 + quad * 4;
                const int b = row0v >> 11;
                const int s0 = row0v & (SEQL - 1);
                #pragma unroll
                for (int nh = 0; nh < 2; ++nh)
                    #pragma unroll
                    for (int j = 0; j < 2; ++j) {
                        const int cw = colbase + nh * 128 + wc * 32 + j * 16 + ml;
                        const int h = cw >> 6, d = cw & 63;
                        const float bb = bias[cw];
                        bf16 tmp[4];
                        #pragma unroll
                        for (int rg = 0; rg < 4; ++rg)
                            tmp[rg] = __float2bfloat16(acc[mh * 4 + i][nh * 2 + j][rg] + bb);
                        *(uint2*)&outb[(((size_t)(b * NH + h)) * DH + d) * SEQL + s0] =
                            *(const uint2*)tmp;
                    }
            }
    } else {
        #pragma unroll
        for (int mh = 0; mh < 2; ++mh)
            #pragma unroll
            for (int i = 0; i < 4; ++i)
                #pragma unroll
                for (int rg = 0; rg < 4; ++rg) {
                    const int row = bm * 256 + mh * 128 + wr * 64 + i * 16 + quad * 4 + rg;
                    const int b = row >> 11;
                    const int s = row & (SEQL - 1);
                    #pragma unroll
                    for (int nh = 0; nh < 2; ++nh)
                        #pragma unroll
                        for (int j = 0; j < 2; ++j) {
                            const int cw = colbase + nh * 128 + wc * 32 + j * 16 + ml;
                            const int h = cw >> 6, d = cw & 63;
                            outb[(((size_t)(b * NH + h)) * SEQL + s) * DH + d] =
                                __float2bfloat16((acc[mh * 4 + i][nh * 2 + j][rg] + bias[cw]) * oscale);
                        }
                }
    }
}

// ---------------------------------------------------------------------------
// O-proj GEMM v3: 128x64 tiles, 2 K-steps per barrier. grid (16,32), block 256.
// ---------------------------------------------------------------------------
__global__ __launch_bounds__(256) void oproj_gemm(
    const bf16* __restrict__ zb, const bf16* __restrict__ Bt,
    const float* __restrict__ bo, float* __restrict__ out)
{
    __shared__ __align__(16) bf16 As[2][128 * 32];
    __shared__ __align__(16) bf16 Bs[2][64 * 32];

    const int t = threadIdx.x;
    const int lane = t & 63, w = t >> 6;
    const int ml = lane & 15, quad = lane >> 4;
    const int wr = w >> 1, wc = w & 1;
    const int bn = blockIdx.x, bm = blockIdx.y;

    const bf16* A0 = zb + (size_t)(bm * 128) * DM;
    const bf16* B0 = Bt + (size_t)(bn * 64) * DM;

    f32x4 acc[4][2];
    #pragma unroll
    for (int i = 0; i < 4; ++i)
        #pragma unroll
        for (int j = 0; j < 2; ++j) acc[i][j] = (f32x4){0.f, 0.f, 0.f, 0.f};

    const int r0 = t >> 2, c0 = (t & 3) * 8;
    const int f1 = t + 256;
    const int r1 = f1 >> 2, c1 = (f1 & 3) * 8;

    for (int kt = 0; kt < DM / 64; ++kt) {
        const int k0 = kt * 64;
        __syncthreads();
        #pragma unroll
        for (int half = 0; half < 2; ++half) {
            const int kh = k0 + half * 32;
            gl_lds16(A0 + (size_t)r0 * DM + kh + c0, &As[half][t * 8]);
            gl_lds16(A0 + (size_t)r1 * DM + kh + c1, &As[half][f1 * 8]);
            gl_lds16(B0 + (size_t)r0 * DM + kh + c0, &Bs[half][t * 8]);
        }
        __syncthreads();
        #pragma unroll
        for (int half = 0; half < 2; ++half) {
            bf16x8 af[4], bfr[2];
            #pragma unroll
            for (int i = 0; i < 4; ++i)
                af[i] = *(const bf16x8*)&As[half][(wr * 64 + i * 16 + ml) * 32 + quad * 8];
            #pragma unroll
            for (int j = 0; j < 2; ++j)
                bfr[j] = *(const bf16x8*)&Bs[half][(wc * 32 + j * 16 + ml) * 32 + quad * 8];
            #pragma unroll
            for (int i = 0; i < 4; ++i)
                #pragma unroll
                for (int j = 0; j < 2; ++j)
                    acc[i][j] = __builtin_amdgcn_mfma_f32_16x16x32_bf16(af[i], bfr[j], acc[i][j], 0, 0, 0);
        }
    }

    float bb[2];
    #pragma unroll
    for (int j = 0; j < 2; ++j) bb[j] = bo[bn * 64 + wc * 32 + j * 16 + ml];

    #pragma unroll
    for (int i = 0; i < 4; ++i) {
        #pragma unroll
        for (int rg = 0; rg < 4; ++rg) {
            const int row = bm * 128 + wr * 64 + i * 16 + quad * 4 + rg;
            #pragma unroll
            for (int j = 0; j < 2; ++j) {
                const int col = bn * 64 + wc * 32 + j * 16 + ml;
                out[(size_t)row * DM + col] = acc[i][j][rg] + bb[j];
            }
        }
    }
}

// ---------------------------------------------------------------------------
// MFMA flash attention v8 (round-2 version, best measured): PAIRED Q-TILES.
// Block = 512 thr (8 waves) handles q-tiles a=blockIdx.y and b=31-a of one
// (batch,head): work = (a+1)+(32-a) = 33 tile-iters for EVERY block.
// grid (bh=32, pair=16), block 512.
// ---------------------------------------------------------------------------
__global__ __launch_bounds__(512) void attn_kernel(
    const bf16* __restrict__ qg, const bf16* __restrict__ kg, const bf16* __restrict__ vtg,
    bf16* __restrict__ z)
{
    __shared__ __align__(16) bf16 KsS[64 * 64];   // 8192 B, swizzled [kv][d]
    __shared__ __align__(16) bf16 VtS[64 * 64];   // 8192 B, swizzled [d][s_local]
    __shared__ __align__(16) bf16 PsS[8][16 * LDK];  // 18432 B (per-wave P tiles)

    const int t    = threadIdx.x;
    const int lane = t & 63;
    const int w    = t >> 6;          // 0..7
    const int m    = lane & 15;
    const int quad = lane >> 4;
    const int wg   = w & 3;           // row-group within its tile
    const int half = w >> 2;          // kv half in phase 2

    const int bh = blockIdx.x;
    const int b  = bh >> 4;
    const int h  = bh & 15;
    const int qa = blockIdx.y;        // 0..15
    const int qb = 31 - qa;           // 16..31
    const int q0a = qa * 64;
    const int q0b = qb * 64;

    const size_t base   = (size_t)bh * SEQL * DH;  // q/k base ([b,h,s,d])
    const size_t vtbase = (size_t)bh * DH * SEQL;  // v^T base ([b,h,d,s])

    const int s  = t;
    const int rs = s >> 3, cs = (s & 7) ^ (rs & 7);

    bf16x8 aq[2], aqB[2];
    {
        const int myq = (w < 4) ? (q0a + w * 16) : (q0b + wg * 16);
        const bf16* qp = qg + base + (size_t)(myq + m) * DH + quad * 8;
        aq[0] = *(const bf16x8*)(qp);
        aq[1] = *(const bf16x8*)(qp + 32);
        const bf16* qpb = qg + base + (size_t)(q0b + wg * 16 + m) * DH + quad * 8;
        aqB[0] = *(const bf16x8*)(qpb);
        aqB[1] = *(const bf16x8*)(qpb + 32);
    }

    const short ob = (m == 0) ? (short)0x3F80 : (short)0;
    const bf16x8 bones = {ob, ob, ob, ob, ob, ob, ob, ob};

    f32x4 zacc[4];
    #pragma unroll
    for (int nt = 0; nt < 4; ++nt) zacc[nt] = (f32x4){0.f, 0.f, 0.f, 0.f};
    f32x4 lacc = (f32x4){0.f, 0.f, 0.f, 0.f};

    bf16* Psw = PsS[w];

    for (int kt = 0; kt <= qb; ++kt) {
        __syncthreads();
        {
            const int kc = kt * 64;
            gl_lds16(kg + base + (size_t)(kc + rs) * DH + cs * 8, &KsS[s * 8]);
            gl_lds16(vtg + vtbase + (size_t)rs * SEQL + kc + cs * 8, &VtS[s * 8]);
        }
        __syncthreads();

        if (kt <= qa) {
            f32x4 sc[4];
            #pragma unroll
            for (int nt = 0; nt < 4; ++nt) sc[nt] = (f32x4){0.f, 0.f, 0.f, 0.f};
            __builtin_amdgcn_s_setprio(1);
            #pragma unroll
            for (int ks = 0; ks < 2; ++ks) {
                #pragma unroll
                for (int nt = 0; nt < 4; ++nt) {
                    const int row = nt * 16 + m;
                    const int pc  = ((ks << 2) + quad) ^ (m & 7);
                    const bf16x8 bk = *(const bf16x8*)(&KsS[row * 64 + pc * 8]);
                    sc[nt] = __builtin_amdgcn_mfma_f32_16x16x32_bf16(aq[ks], bk, sc[nt], 0, 0, 0);
                }
            }
            __builtin_amdgcn_s_setprio(0);
            if (kt == qa && w < 4) {
                #pragma unroll
                for (int nt = 0; nt < 4; ++nt) {
                    const int col = nt * 16 + m;
                    #pragma unroll
                    for (int rg = 0; rg < 4; ++rg) {
                        const int row = wg * 16 + quad * 4 + rg;
                        if (col > row) sc[nt][rg] = -1e30f;
                    }
                }
            }

            #pragma unroll
            for (int nt = 0; nt < 4; ++nt)
                #pragma unroll
                for (int rg = 0; rg < 4; ++rg)
                    Psw[(quad * 4 + rg) * LDK + nt * 16 + m] =
                        __float2bfloat16(__builtin_exp2f(sc[nt][rg]));

            __builtin_amdgcn_s_setprio(1);
            #pragma unroll
            for (int ks = 0; ks < 2; ++ks) {
                const bf16x8 ap = *(const bf16x8*)(&Psw[m * LDK + ks * 32 + quad * 8]);
                lacc = __builtin_amdgcn_mfma_f32_16x16x32_bf16(ap, bones, lacc, 0, 0, 0);
                #pragma unroll
                for (int nt = 0; nt < 4; ++nt) {
                    const int row = nt * 16 + m;
                    const int pc  = ((ks << 2) + quad) ^ (m & 7);
                    const bf16x8 bv = *(const bf16x8*)(&VtS[row * 64 + pc * 8]);
                    zacc[nt] = __builtin_amdgcn_mfma_f32_16x16x32_bf16(ap, bv, zacc[nt], 0, 0, 0);
                }
            }
            __builtin_amdgcn_s_setprio(0);

            if (kt == qa && w < 4) {
                float invl[4];
                #pragma unroll
                for (int rg = 0; rg < 4; ++rg)
                    invl[rg] = 1.f / __shfl(lacc[rg], quad * 16);
                #pragma unroll
                for (int nt = 0; nt < 4; ++nt) {
                    const int d = nt * 16 + m;
                    #pragma unroll
                    for (int rg = 0; rg < 4; ++rg) {
                        const int qrow = q0a + wg * 16 + quad * 4 + rg;
                        z[(((size_t)b * SEQL + qrow) * NH + h) * DH + d] =
                            __float2bfloat16(zacc[nt][rg] * invl[rg]);
                    }
                }
                #pragma unroll
                for (int nt = 0; nt < 4; ++nt) zacc[nt] = (f32x4){0.f, 0.f, 0.f, 0.f};
                lacc = (f32x4){0.f, 0.f, 0.f, 0.f};
                aq[0] = aqB[0]; aq[1] = aqB[1];
            }
        } else {
            f32x4 sc[2];
            sc[0] = (f32x4){0.f, 0.f, 0.f, 0.f};
            sc[1] = (f32x4){0.f, 0.f, 0.f, 0.f};
            __builtin_amdgcn_s_setprio(1);
            #pragma unroll
            for (int ks = 0; ks < 2; ++ks) {
                #pragma unroll
                for (int nt = 0; nt < 2; ++nt) {
                    const int row = half * 32 + nt * 16 + m;
                    const int pc  = ((ks << 2) + quad) ^ (m & 7);
                    const bf16x8 bk = *(const bf16x8*)(&KsS[row * 64 + pc * 8]);
                    sc[nt] = __builtin_amdgcn_mfma_f32_16x16x32_bf16(aq[ks], bk, sc[nt], 0, 0, 0);
                }
            }
            __builtin_amdgcn_s_setprio(0);
            if (kt == qb) {
                #pragma unroll
                for (int nt = 0; nt < 2; ++nt) {
                    const int col = half * 32 + nt * 16 + m;
                    #pragma unroll
                    for (int rg = 0; rg < 4; ++rg) {
                        const int row = wg * 16 + quad * 4 + rg;
                        if (col > row) sc[nt][rg] = -1e30f;
                    }
                }
            }

            #pragma unroll
            for (int nt = 0; nt < 2; ++nt)
                #pragma unroll
                for (int rg = 0; rg < 4; ++rg)
                    Psw[(quad * 4 + rg) * LDK + nt * 16 + m] =
                        __float2bfloat16(__builtin_exp2f(sc[nt][rg]));

            __builtin_amdgcn_s_setprio(1);
            {
                const bf16x8 ap = *(const bf16x8*)(&Psw[m * LDK + quad * 8]);
                lacc = __builtin_amdgcn_mfma_f32_16x16x32_bf16(ap, bones, lacc, 0, 0, 0);
                #pragma unroll
                for (int nt = 0; nt < 4; ++nt) {
                    const int row = nt * 16 + m;
                    const int pc  = ((half << 2) + quad) ^ (m & 7);
                    const bf16x8 bv = *(const bf16x8*)(&VtS[row * 64 + pc * 8]);
                    zacc[nt] = __builtin_amdgcn_mfma_f32_16x16x32_bf16(ap, bv, zacc[nt], 0, 0, 0);
                }
            }
            __builtin_amdgcn_s_setprio(0);
        }
    }

    __syncthreads();
    if (w < 4) {
        float* zs = (w < 2) ? ((float*)KsS) + (size_t)w * 1024
                            : ((float*)VtS) + (size_t)(w - 2) * 1024;
        #pragma unroll
        for (int nt = 0; nt < 4; ++nt)
            #pragma unroll
            for (int rg = 0; rg < 4; ++rg)
                zs[lane * 16 + nt * 4 + rg] = zacc[nt][rg];
        float* ls = ((float*)PsS) + w * 256;
        #pragma unroll
        for (int rg = 0; rg < 4; ++rg) ls[lane * 4 + rg] = lacc[rg];
    }
    __syncthreads();
    if (w >= 4) {
        const int ww = w - 4;
        const float* zs = (ww < 2) ? ((const float*)KsS) + (size_t)ww * 1024
                                   : ((const float*)VtS) + (size_t)(ww - 2) * 1024;
        const float* ls = ((const float*)PsS) + ww * 256;
        #pragma unroll
        for (int nt = 0; nt < 4; ++nt)
            #pragma unroll
            for (int rg = 0; rg < 4; ++rg)
                zacc[nt][rg] += zs[lane * 16 + nt * 4 + rg];
        #pragma unroll
        for (int rg = 0; rg < 4; ++rg) lacc[rg] += ls[lane * 4 + rg];

        float invl[4];
        #pragma unroll
        for (int rg = 0; rg < 4; ++rg)
            invl[rg] = 1.f / __shfl(lacc[rg], quad * 16);
        #pragma unroll
        for (int nt = 0; nt < 4; ++nt) {
            const int d = nt * 16 + m;
            #pragma unroll
            for (int rg = 0; rg < 4; ++rg) {
                const int qrow = q0b + wg * 16 + quad * 4 + rg;
                z[(((size_t)b * SEQL + qrow) * NH + h) * DH + d] =
                    __float2bfloat16(zacc[nt][rg] * invl[rg]);
            }
        }
    }
}

// ---------------------------------------------------------------------------
extern "C" void kernel_launch(void* const* d_in, const int* in_sizes, int n_in,
                              void* d_out, int out_size, void* d_ws, size_t ws_size,
                              hipStream_t stream)
{
    const float* x  = (const float*)d_in[0];
    const float* Wq = (const float*)d_in[1];
    const float* Wk = (const float*)d_in[2];
    const float* Wv = (const float*)d_in[3];
    const float* Wo = (const float*)d_in[4];
    const float* bq = (const float*)d_in[5];
    const float* bk = (const float*)d_in[6];
    const float* bv = (const float*)d_in[7];
    const float* bo = (const float*)d_in[8];
    float* out = (float*)d_out;

    const size_t TOK = (size_t)BATCH * SEQL;             // 4096
    const size_t QKV = TOK * DM;                         // 4M elems
    bf16* xb  = (bf16*)d_ws;                             // 4M
    bf16* Wt  = xb + QKV;                                // 4 x 1M
    bf16* qkv = Wt + 4 * (size_t)DM * DM;                // 3 x 4M
    bf16* zb  = qkv + 3 * QKV;                           // 4M   (48 MB total)

    prep_kernel<<<dim3(16, 16, 5), 256, 0, stream>>>(x, Wq, Wk, Wv, Wo, Wt, xb);
    qkv_gemm<<<dim3(12, 16), 512, 0, stream>>>(xb, Wt, bq, bk, bv, qkv);
    attn_kernel<<<dim3(BATCH * NH, 16), 512, 0, stream>>>(
        qkv, qkv + QKV, qkv + 2 * QKV, zb);
    oproj_gemm<<<dim3(16, 32), 256, 0, stream>>>(zb, Wt + 3 * (size_t)DM * DM, bo, out);
}

// Round 6
// 182.282 us; speedup vs baseline: 1.0930x; 1.0297x over previous
//
#include <hip/hip_runtime.h>
#include <hip/hip_bf16.h>

#define BATCH 2
#define SEQL 2048
#define NH 16
#define DH 64
#define DM 1024
#define LDK 72   // attn P-tile LDS row stride (bf16): 144B rows -> 2-way (free)
// Q pre-scale folded into qkv_gemm epilogue: 1/sqrt(64) * log2(e)
#define QSCALE 0.1803368801111244f

typedef __hip_bfloat16 bf16;
typedef __attribute__((ext_vector_type(8)))  short bf16x8;
typedef __attribute__((ext_vector_type(4)))  float f32x4;

__device__ __forceinline__ void gl_lds16(const void* g, void* l) {
    __builtin_amdgcn_global_load_lds(
        (const __attribute__((address_space(1))) unsigned int*)g,
        (__attribute__((address_space(3))) unsigned int*)l, 16, 0, 0);
}

// ---------------------------------------------------------------------------
// Prep (fused): z<4 -> weight transpose to bf16 Bt[n][k]; z==4 -> x fp32->bf16
// (grid-stride). grid (16,16,5), block 256.
// ---------------------------------------------------------------------------
__global__ __launch_bounds__(256) void prep_kernel(
    const float* __restrict__ x,
    const float* __restrict__ Wq, const float* __restrict__ Wk,
    const float* __restrict__ Wv, const float* __restrict__ Wo,
    bf16* __restrict__ Wt, bf16* __restrict__ xb)
{
    const int zi = blockIdx.z;
    if (zi == 4) {
        const int bid = blockIdx.y * 16 + blockIdx.x;
        const size_t base = ((size_t)bid * 256 + threadIdx.x) * 4;
        #pragma unroll
        for (int it = 0; it < 16; ++it) {
            const size_t i = base + (size_t)it * 262144;
            const float4 v = *(const float4*)(x + i);
            bf16 o[4];
            o[0] = __float2bfloat16(v.x); o[1] = __float2bfloat16(v.y);
            o[2] = __float2bfloat16(v.z); o[3] = __float2bfloat16(v.w);
            *(uint2*)(xb + i) = *(const uint2*)o;
        }
        return;
    }

    __shared__ float ts[64][65];
    const float* src = (zi == 0) ? Wq : (zi == 1) ? Wk : (zi == 2) ? Wv : Wo;
    bf16* dst = Wt + (size_t)zi * DM * DM;
    const int row0 = blockIdx.y * 64;
    const int col0 = blockIdx.x * 64;
    const int tx = threadIdx.x & 63;
    const int ty = threadIdx.x >> 6;

    if (zi < 3) {
        const int h = col0 >> 6;
        #pragma unroll
        for (int i = 0; i < 16; ++i) {
            const int r = ty + 4 * i;
            ts[r][tx] = src[h * (DM * DH) + (row0 + r) * DH + tx];
        }
    } else {
        #pragma unroll
        for (int i = 0; i < 16; ++i) {
            const int r = ty + 4 * i;
            ts[r][tx] = src[(size_t)(row0 + r) * DM + col0 + tx];
        }
    }
    __syncthreads();
    #pragma unroll
    for (int i = 0; i < 16; ++i) {
        const int rr = ty + 4 * i;
        dst[(size_t)(col0 + rr) * DM + row0 + tx] = __float2bfloat16(ts[tx][rr]);
    }
}

// ---------------------------------------------------------------------------
// QKV GEMM v3 (round-3 version, best measured): 128x128 tiles, 2 K-steps per
// barrier, round-6 epilogue. grid (8, 32, 3), block 256.
// ---------------------------------------------------------------------------
__global__ __launch_bounds__(256) void qkv_gemm(
    const bf16* __restrict__ xb, const bf16* __restrict__ Wt,
    const float* __restrict__ bq, const float* __restrict__ bk, const float* __restrict__ bv,
    bf16* __restrict__ qkv)
{
    __shared__ __align__(16) bf16 As[2][128 * 32];
    __shared__ __align__(16) bf16 Bs[2][128 * 32];

    const int t = threadIdx.x;
    const int lane = t & 63, w = t >> 6;
    const int ml = lane & 15, quad = lane >> 4;
    const int wr = w >> 1, wc = w & 1;
    const int bn = blockIdx.x, bm = blockIdx.y, which = blockIdx.z;

    const bf16* A0 = xb + (size_t)(bm * 128) * DM;
    const bf16* B0 = Wt + (size_t)which * DM * DM + (size_t)(bn * 128) * DM;
    const float* bias = (which == 0) ? bq : (which == 1) ? bk : bv;
    bf16* outb = qkv + (size_t)which * (BATCH * SEQL * NH * DH);
    const float oscale = (which == 0) ? QSCALE : 1.0f;

    f32x4 acc[4][4];
    #pragma unroll
    for (int i = 0; i < 4; ++i)
        #pragma unroll
        for (int j = 0; j < 4; ++j) acc[i][j] = (f32x4){0.f, 0.f, 0.f, 0.f};

    const int r0 = t >> 2, c0 = (t & 3) * 8;
    const int f1 = t + 256;
    const int r1 = f1 >> 2, c1 = (f1 & 3) * 8;

    for (int kt = 0; kt < DM / 64; ++kt) {
        const int k0 = kt * 64;
        __syncthreads();
        #pragma unroll
        for (int half = 0; half < 2; ++half) {
            const int kh = k0 + half * 32;
            gl_lds16(A0 + (size_t)r0 * DM + kh + c0, &As[half][t * 8]);
            gl_lds16(A0 + (size_t)r1 * DM + kh + c1, &As[half][f1 * 8]);
            gl_lds16(B0 + (size_t)r0 * DM + kh + c0, &Bs[half][t * 8]);
            gl_lds16(B0 + (size_t)r1 * DM + kh + c1, &Bs[half][f1 * 8]);
        }
        __syncthreads();
        #pragma unroll
        for (int half = 0; half < 2; ++half) {
            bf16x8 af[4], bfr[4];
            #pragma unroll
            for (int i = 0; i < 4; ++i)
                af[i] = *(const bf16x8*)&As[half][(wr * 64 + i * 16 + ml) * 32 + quad * 8];
            #pragma unroll
            for (int j = 0; j < 4; ++j)
                bfr[j] = *(const bf16x8*)&Bs[half][(wc * 64 + j * 16 + ml) * 32 + quad * 8];
            #pragma unroll
            for (int i = 0; i < 4; ++i)
                #pragma unroll
                for (int j = 0; j < 4; ++j)
                    acc[i][j] = __builtin_amdgcn_mfma_f32_16x16x32_bf16(af[i], bfr[j], acc[i][j], 0, 0, 0);
        }
    }

    float bb[4];
    #pragma unroll
    for (int j = 0; j < 4; ++j) bb[j] = bias[bn * 128 + wc * 64 + j * 16 + ml];

    if (which == 2) {
        #pragma unroll
        for (int i = 0; i < 4; ++i) {
            const int row0v = bm * 128 + wr * 64 + i * 16 + quad * 4;
            const int b = row0v >> 11;
            const int s0 = row0v & (SEQL - 1);
            #pragma unroll
            for (int j = 0; j < 4; ++j) {
                const int col = bn * 128 + wc * 64 + j * 16 + ml;
                const int h = col >> 6, d = col & 63;
                bf16 tmp[4];
                #pragma unroll
                for (int rg = 0; rg < 4; ++rg)
                    tmp[rg] = __float2bfloat16(acc[i][j][rg] + bb[j]);
                *(uint2*)&outb[(((size_t)(b * NH + h)) * DH + d) * SEQL + s0] =
                    *(const uint2*)tmp;
            }
        }
    } else {
        #pragma unroll
        for (int i = 0; i < 4; ++i) {
            #pragma unroll
            for (int rg = 0; rg < 4; ++rg) {
                const int row = bm * 128 + wr * 64 + i * 16 + quad * 4 + rg;
                const int b = row >> 11;
                const int s = row & (SEQL - 1);
                #pragma unroll
                for (int j = 0; j < 4; ++j) {
                    const int col = bn * 128 + wc * 64 + j * 16 + ml;
                    const int h = col >> 6, d = col & 63;
                    outb[(((size_t)(b * NH + h)) * SEQL + s) * DH + d] =
                        __float2bfloat16((acc[i][j][rg] + bb[j]) * oscale);
                }
            }
        }
    }
}

// ---------------------------------------------------------------------------
// O-proj GEMM v3: 128x64 tiles, 2 K-steps per barrier. grid (16,32), block 256.
// ---------------------------------------------------------------------------
__global__ __launch_bounds__(256) void oproj_gemm(
    const bf16* __restrict__ zb, const bf16* __restrict__ Bt,
    const float* __restrict__ bo, float* __restrict__ out)
{
    __shared__ __align__(16) bf16 As[2][128 * 32];
    __shared__ __align__(16) bf16 Bs[2][64 * 32];

    const int t = threadIdx.x;
    const int lane = t & 63, w = t >> 6;
    const int ml = lane & 15, quad = lane >> 4;
    const int wr = w >> 1, wc = w & 1;
    const int bn = blockIdx.x, bm = blockIdx.y;

    const bf16* A0 = zb + (size_t)(bm * 128) * DM;
    const bf16* B0 = Bt + (size_t)(bn * 64) * DM;

    f32x4 acc[4][2];
    #pragma unroll
    for (int i = 0; i < 4; ++i)
        #pragma unroll
        for (int j = 0; j < 2; ++j) acc[i][j] = (f32x4){0.f, 0.f, 0.f, 0.f};

    const int r0 = t >> 2, c0 = (t & 3) * 8;
    const int f1 = t + 256;
    const int r1 = f1 >> 2, c1 = (f1 & 3) * 8;

    for (int kt = 0; kt < DM / 64; ++kt) {
        const int k0 = kt * 64;
        __syncthreads();
        #pragma unroll
        for (int half = 0; half < 2; ++half) {
            const int kh = k0 + half * 32;
            gl_lds16(A0 + (size_t)r0 * DM + kh + c0, &As[half][t * 8]);
            gl_lds16(A0 + (size_t)r1 * DM + kh + c1, &As[half][f1 * 8]);
            gl_lds16(B0 + (size_t)r0 * DM + kh + c0, &Bs[half][t * 8]);
        }
        __syncthreads();
        #pragma unroll
        for (int half = 0; half < 2; ++half) {
            bf16x8 af[4], bfr[2];
            #pragma unroll
            for (int i = 0; i < 4; ++i)
                af[i] = *(const bf16x8*)&As[half][(wr * 64 + i * 16 + ml) * 32 + quad * 8];
            #pragma unroll
            for (int j = 0; j < 2; ++j)
                bfr[j] = *(const bf16x8*)&Bs[half][(wc * 32 + j * 16 + ml) * 32 + quad * 8];
            #pragma unroll
            for (int i = 0; i < 4; ++i)
                #pragma unroll
                for (int j = 0; j < 2; ++j)
                    acc[i][j] = __builtin_amdgcn_mfma_f32_16x16x32_bf16(af[i], bfr[j], acc[i][j], 0, 0, 0);
        }
    }

    float bb[2];
    #pragma unroll
    for (int j = 0; j < 2; ++j) bb[j] = bo[bn * 64 + wc * 32 + j * 16 + ml];

    #pragma unroll
    for (int i = 0; i < 4; ++i) {
        #pragma unroll
        for (int rg = 0; rg < 4; ++rg) {
            const int row = bm * 128 + wr * 64 + i * 16 + quad * 4 + rg;
            #pragma unroll
            for (int j = 0; j < 2; ++j) {
                const int col = bn * 64 + wc * 32 + j * 16 + ml;
                out[(size_t)row * DM + col] = acc[i][j][rg] + bb[j];
            }
        }
    }
}

// ---------------------------------------------------------------------------
// MFMA flash attention v11: v8 paired-q-tiles structure + 128-kv STAGES.
// One barrier-pair stages 128 kv rows (K [128][64], V^T [64][128] 16-deep XOR
// swizzle); the v8 64-kv compute body runs twice per stage (kt = 2c+c2) with
// only a +c2*64 row offset. Barrier-pairs per block halve (avg 24.5 -> 12.5);
// staged bytes / MFMA count / P machinery identical to v8.
// grid (bh=32, pair=16), block 512.  LDS 51.2 KB -> 2 blocks/CU (grid-limited).
// ---------------------------------------------------------------------------
__global__ __launch_bounds__(512) void attn_kernel(
    const bf16* __restrict__ qg, const bf16* __restrict__ kg, const bf16* __restrict__ vtg,
    bf16* __restrict__ z)
{
    __shared__ __align__(16) bf16 KsS[128 * 64];     // 16 KB, [kv][d], 8-deep swz
    __shared__ __align__(16) bf16 VtS[64 * 128];     // 16 KB, [d][kv], 16-deep swz
    __shared__ __align__(16) bf16 PsS[8][16 * LDK];  // 18 KB per-wave P tiles

    const int t    = threadIdx.x;
    const int lane = t & 63;
    const int w    = t >> 6;          // 0..7
    const int m    = lane & 15;
    const int quad = lane >> 4;
    const int wg   = w & 3;           // row-group within its tile
    const int half = w >> 2;          // kv half in phase 2

    const int bh = blockIdx.x;
    const int b  = bh >> 4;
    const int h  = bh & 15;
    const int qa = blockIdx.y;        // 0..15
    const int qb = 31 - qa;           // 16..31
    const int q0a = qa * 64;
    const int q0b = qb * 64;

    const size_t base   = (size_t)bh * SEQL * DH;  // q/k base ([b,h,s,d])
    const size_t vtbase = (size_t)bh * DH * SEQL;  // v^T base ([b,h,d,s])

    // staging slots: 512 thr x 2 slots x 16B per array (1024 slots = 16KB each)
    const int s0 = t, s1 = t + 512;
    const int kr0 = s0 >> 3, kc0 = (s0 & 7) ^ (kr0 & 7);
    const int kr1 = s1 >> 3, kc1 = (s1 & 7) ^ (kr1 & 7);
    const int vr0 = s0 >> 4, vc0 = (s0 & 15) ^ (vr0 & 15);
    const int vr1 = s1 >> 4, vc1 = (s1 & 15) ^ (vr1 & 15);

    bf16x8 aq[2], aqB[2];
    {
        const int myq = (w < 4) ? (q0a + w * 16) : (q0b + wg * 16);
        const bf16* qp = qg + base + (size_t)(myq + m) * DH + quad * 8;
        aq[0] = *(const bf16x8*)(qp);
        aq[1] = *(const bf16x8*)(qp + 32);
        const bf16* qpb = qg + base + (size_t)(q0b + wg * 16 + m) * DH + quad * 8;
        aqB[0] = *(const bf16x8*)(qpb);
        aqB[1] = *(const bf16x8*)(qpb + 32);
    }

    const short ob = (m == 0) ? (short)0x3F80 : (short)0;
    const bf16x8 bones = {ob, ob, ob, ob, ob, ob, ob, ob};

    f32x4 zacc[4];
    #pragma unroll
    for (int nt = 0; nt < 4; ++nt) zacc[nt] = (f32x4){0.f, 0.f, 0.f, 0.f};
    f32x4 lacc = (f32x4){0.f, 0.f, 0.f, 0.f};

    bf16* Psw = PsS[w];

    const int CB = (qb >> 1) + 1;     // 128-kv stages
    for (int c = 0; c < CB; ++c) {
        __syncthreads();              // prev stage's reads complete
        {
            const int kc = c * 128;
            gl_lds16(kg + base + (size_t)(kc + kr0) * DH + kc0 * 8, &KsS[s0 * 8]);
            gl_lds16(kg + base + (size_t)(kc + kr1) * DH + kc1 * 8, &KsS[s1 * 8]);
            gl_lds16(vtg + vtbase + (size_t)vr0 * SEQL + kc + vc0 * 8, &VtS[s0 * 8]);
            gl_lds16(vtg + vtbase + (size_t)vr1 * SEQL + kc + vc1 * 8, &VtS[s1 * 8]);
        }
        __syncthreads();              // staging visible (vmcnt drain)

        #pragma unroll
        for (int c2 = 0; c2 < 2; ++c2) {
            const int kt = 2 * c + c2;
            if (kt > qb) break;       // uniform across block
            const int co = c2 * 64;   // kv row offset within the stage

            if (kt <= qa) {
                // ---------- phase 1: waves 0-3 tile a, 4-7 tile b ----------
                f32x4 sc[4];
                #pragma unroll
                for (int nt = 0; nt < 4; ++nt) sc[nt] = (f32x4){0.f, 0.f, 0.f, 0.f};
                __builtin_amdgcn_s_setprio(1);
                #pragma unroll
                for (int ks = 0; ks < 2; ++ks) {
                    #pragma unroll
                    for (int nt = 0; nt < 4; ++nt) {
                        const int rw = co + nt * 16 + m;
                        const int pc = ((ks << 2) + quad) ^ (m & 7);
                        const bf16x8 bk = *(const bf16x8*)(&KsS[rw * 64 + pc * 8]);
                        sc[nt] = __builtin_amdgcn_mfma_f32_16x16x32_bf16(aq[ks], bk, sc[nt], 0, 0, 0);
                    }
                }
                __builtin_amdgcn_s_setprio(0);
                if (kt == qa && w < 4) {
                    #pragma unroll
                    for (int nt = 0; nt < 4; ++nt) {
                        const int col = nt * 16 + m;
                        #pragma unroll
                        for (int rg = 0; rg < 4; ++rg) {
                            const int row = wg * 16 + quad * 4 + rg;
                            if (col > row) sc[nt][rg] = -1e30f;
                        }
                    }
                }

                #pragma unroll
                for (int nt = 0; nt < 4; ++nt)
                    #pragma unroll
                    for (int rg = 0; rg < 4; ++rg)
                        Psw[(quad * 4 + rg) * LDK + nt * 16 + m] =
                            __float2bfloat16(__builtin_exp2f(sc[nt][rg]));

                __builtin_amdgcn_s_setprio(1);
                #pragma unroll
                for (int ks = 0; ks < 2; ++ks) {
                    const bf16x8 ap = *(const bf16x8*)(&Psw[m * LDK + ks * 32 + quad * 8]);
                    lacc = __builtin_amdgcn_mfma_f32_16x16x32_bf16(ap, bones, lacc, 0, 0, 0);
                    #pragma unroll
                    for (int nt = 0; nt < 4; ++nt) {
                        const int dr = nt * 16 + m;
                        const int vc = (c2 * 8 + (ks << 2) + quad) ^ m;
                        const bf16x8 bv = *(const bf16x8*)(&VtS[dr * 128 + vc * 8]);
                        zacc[nt] = __builtin_amdgcn_mfma_f32_16x16x32_bf16(ap, bv, zacc[nt], 0, 0, 0);
                    }
                }
                __builtin_amdgcn_s_setprio(0);

                if (kt == qa && w < 4) {
                    // finalize + write tile a, switch to tile b
                    float invl[4];
                    #pragma unroll
                    for (int rg = 0; rg < 4; ++rg)
                        invl[rg] = 1.f / __shfl(lacc[rg], quad * 16);
                    #pragma unroll
                    for (int nt = 0; nt < 4; ++nt) {
                        const int d = nt * 16 + m;
                        #pragma unroll
                        for (int rg = 0; rg < 4; ++rg) {
                            const int qrow = q0a + wg * 16 + quad * 4 + rg;
                            z[(((size_t)b * SEQL + qrow) * NH + h) * DH + d] =
                                __float2bfloat16(zacc[nt][rg] * invl[rg]);
                        }
                    }
                    #pragma unroll
                    for (int nt = 0; nt < 4; ++nt) zacc[nt] = (f32x4){0.f, 0.f, 0.f, 0.f};
                    lacc = (f32x4){0.f, 0.f, 0.f, 0.f};
                    aq[0] = aqB[0]; aq[1] = aqB[1];
                }
            } else {
                // ---------- phase 2: all 8 waves on tile b, kv halves split ----
                f32x4 sc[2];
                sc[0] = (f32x4){0.f, 0.f, 0.f, 0.f};
                sc[1] = (f32x4){0.f, 0.f, 0.f, 0.f};
                __builtin_amdgcn_s_setprio(1);
                #pragma unroll
                for (int ks = 0; ks < 2; ++ks) {
                    #pragma unroll
                    for (int nt = 0; nt < 2; ++nt) {
                        const int rw = co + half * 32 + nt * 16 + m;
                        const int pc = ((ks << 2) + quad) ^ (m & 7);
                        const bf16x8 bk = *(const bf16x8*)(&KsS[rw * 64 + pc * 8]);
                        sc[nt] = __builtin_amdgcn_mfma_f32_16x16x32_bf16(aq[ks], bk, sc[nt], 0, 0, 0);
                    }
                }
                __builtin_amdgcn_s_setprio(0);
                if (kt == qb) {
                    #pragma unroll
                    for (int nt = 0; nt < 2; ++nt) {
                        const int col = half * 32 + nt * 16 + m;
                        #pragma unroll
                        for (int rg = 0; rg < 4; ++rg) {
                            const int row = wg * 16 + quad * 4 + rg;
                            if (col > row) sc[nt][rg] = -1e30f;
                        }
                    }
                }

                #pragma unroll
                for (int nt = 0; nt < 2; ++nt)
                    #pragma unroll
                    for (int rg = 0; rg < 4; ++rg)
                        Psw[(quad * 4 + rg) * LDK + nt * 16 + m] =
                            __float2bfloat16(__builtin_exp2f(sc[nt][rg]));

                __builtin_amdgcn_s_setprio(1);
                {
                    const bf16x8 ap = *(const bf16x8*)(&Psw[m * LDK + quad * 8]);
                    lacc = __builtin_amdgcn_mfma_f32_16x16x32_bf16(ap, bones, lacc, 0, 0, 0);
                    #pragma unroll
                    for (int nt = 0; nt < 4; ++nt) {
                        const int dr = nt * 16 + m;
                        const int vc = (c2 * 8 + (half << 2) + quad) ^ m;
                        const bf16x8 bv = *(const bf16x8*)(&VtS[dr * 128 + vc * 8]);
                        zacc[nt] = __builtin_amdgcn_mfma_f32_16x16x32_bf16(ap, bv, zacc[nt], 0, 0, 0);
                    }
                }
                __builtin_amdgcn_s_setprio(0);
            }
        }
    }

    // ---- combine tile b partials across wave pairs (w, w+4) via LDS ----
    __syncthreads();   // all compute done; K/V LDS reusable as f32 scratch
    if (w < 4) {
        float* zs = (w < 2) ? ((float*)KsS) + (size_t)w * 1024
                            : ((float*)VtS) + (size_t)(w - 2) * 1024;
        #pragma unroll
        for (int nt = 0; nt < 4; ++nt)
            #pragma unroll
            for (int rg = 0; rg < 4; ++rg)
                zs[lane * 16 + nt * 4 + rg] = zacc[nt][rg];
        float* ls = ((float*)PsS) + w * 256;
        #pragma unroll
        for (int rg = 0; rg < 4; ++rg) ls[lane * 4 + rg] = lacc[rg];
    }
    __syncthreads();
    if (w >= 4) {
        const int ww = w - 4;
        const float* zs = (ww < 2) ? ((const float*)KsS) + (size_t)ww * 1024
                                   : ((const float*)VtS) + (size_t)(ww - 2) * 1024;
        const float* ls = ((const float*)PsS) + ww * 256;
        #pragma unroll
        for (int nt = 0; nt < 4; ++nt)
            #pragma unroll
            for (int rg = 0; rg < 4; ++rg)
                zacc[nt][rg] += zs[lane * 16 + nt * 4 + rg];
        #pragma unroll
        for (int rg = 0; rg < 4; ++rg) lacc[rg] += ls[lane * 4 + rg];

        float invl[4];
        #pragma unroll
        for (int rg = 0; rg < 4; ++rg)
            invl[rg] = 1.f / __shfl(lacc[rg], quad * 16);
        #pragma unroll
        for (int nt = 0; nt < 4; ++nt) {
            const int d = nt * 16 + m;
            #pragma unroll
            for (int rg = 0; rg < 4; ++rg) {
                const int qrow = q0b + wg * 16 + quad * 4 + rg;
                z[(((size_t)b * SEQL + qrow) * NH + h) * DH + d] =
                    __float2bfloat16(zacc[nt][rg] * invl[rg]);
            }
        }
    }
}

// ---------------------------------------------------------------------------
extern "C" void kernel_launch(void* const* d_in, const int* in_sizes, int n_in,
                              void* d_out, int out_size, void* d_ws, size_t ws_size,
                              hipStream_t stream)
{
    const float* x  = (const float*)d_in[0];
    const float* Wq = (const float*)d_in[1];
    const float* Wk = (const float*)d_in[2];
    const float* Wv = (const float*)d_in[3];
    const float* Wo = (const float*)d_in[4];
    const float* bq = (const float*)d_in[5];
    const float* bk = (const float*)d_in[6];
    const float* bv = (const float*)d_in[7];
    const float* bo = (const float*)d_in[8];
    float* out = (float*)d_out;

    const size_t TOK = (size_t)BATCH * SEQL;             // 4096
    const size_t QKV = TOK * DM;                         // 4M elems
    bf16* xb  = (bf16*)d_ws;                             // 4M
    bf16* Wt  = xb + QKV;                                // 4 x 1M
    bf16* qkv = Wt + 4 * (size_t)DM * DM;                // 3 x 4M
    bf16* zb  = qkv + 3 * QKV;                           // 4M   (48 MB total)

    prep_kernel<<<dim3(16, 16, 5), 256, 0, stream>>>(x, Wq, Wk, Wv, Wo, Wt, xb);
    qkv_gemm<<<dim3(8, 32, 3), 256, 0, stream>>>(xb, Wt, bq, bk, bv, qkv);
    attn_kernel<<<dim3(BATCH * NH, 16), 512, 0, stream>>>(
        qkv, qkv + QKV, qkv + 2 * QKV, zb);
    oproj_gemm<<<dim3(16, 32), 256, 0, stream>>>(zb, Wt + 3 * (size_t)DM * DM, bo, out);
}